// Round 11
// baseline (106.895 us; speedup 1.0000x reference)
//
#include <hip/hip_runtime.h>
#include <math.h>

#define CLS_NUM 1000
#define FEAT 512
#define GRID 2048

// R2-champion structure, with the final reduction folded into the dist
// kernel via a ticket-based last-block finalize (saves 1 graph node + gap).
// R5 lesson applied: NO per-thread __threadfence() (that was a 372us
// cache-maintenance storm). Ordering instead: each wave drains its own
// bin atomics (s_waitcnt vmcnt(0) -> complete at the device-coherent
// point), then one agent-scope ticket atomic per block; the last block
// reads bins with agent-scope atomic loads (proven correct in R5).
__global__ __launch_bounds__(256) void center_loss_fused(
    const float* __restrict__ xs,
    const void* __restrict__ ys_raw,
    const float* __restrict__ center,
    float* __restrict__ distsum,
    unsigned int* __restrict__ count,
    unsigned int* __restrict__ arrival,
    float* __restrict__ out,
    int n)
{
    // Detect int64 vs int32 labels: for int64 (little-endian) the high
    // 32-bit word of each element is 0 and low word < 1000. For int32,
    // odd words are random labels; all-zero across 16 slots ~ 1e-48.
    const int* y32 = (const int*)ys_raw;
    bool is64 = true;
    #pragma unroll
    for (int k = 0; k < 16; ++k) {
        int lo = y32[2 * k], hi = y32[2 * k + 1];
        if (hi != 0 || (unsigned)lo >= (unsigned)CLS_NUM) is64 = false;
    }
    const long long* y64 = (const long long*)ys_raw;

    const int lane  = threadIdx.x & 63;
    const int wave  = (int)((blockIdx.x * blockDim.x + threadIdx.x) >> 6);
    const int nwave = (int)((gridDim.x * blockDim.x) >> 6);

    // ---- hot loop: byte-identical to the R2 champion ----
    for (int i = wave; i < n; i += nwave) {
        const int y = is64 ? (int)y64[i] : y32[i];
        const float4* xp = (const float4*)(xs + (size_t)i * FEAT);
        const float4* cp = (const float4*)(center + (size_t)y * FEAT);
        float4 x0 = xp[lane];
        float4 x1 = xp[lane + 64];
        float4 c0 = cp[lane];
        float4 c1 = cp[lane + 64];
        float d, s = 0.f;
        d = x0.x - c0.x; s += d * d;
        d = x0.y - c0.y; s += d * d;
        d = x0.z - c0.z; s += d * d;
        d = x0.w - c0.w; s += d * d;
        d = x1.x - c1.x; s += d * d;
        d = x1.y - c1.y; s += d * d;
        d = x1.z - c1.z; s += d * d;
        d = x1.w - c1.w; s += d * d;
        #pragma unroll
        for (int off = 32; off; off >>= 1)
            s += __shfl_xor(s, off, 64);
        if (lane == 0) {
            atomicAdd(&distsum[y], sqrtf(s));
            atomicAdd(&count[y], 1u);
        }
    }

    // ---- last-block finalize (fence-free) ----
    // Drain this wave's outstanding bin atomics to the coherence point.
    asm volatile("s_waitcnt vmcnt(0)" ::: "memory");
    __syncthreads();

    __shared__ unsigned s_ticket;
    if (threadIdx.x == 0)
        s_ticket = __hip_atomic_fetch_add(arrival, 1u, __ATOMIC_ACQ_REL,
                                          __HIP_MEMORY_SCOPE_AGENT);
    __syncthreads();

    if (s_ticket == (unsigned)(gridDim.x - 1)) {
        // All 2047 other blocks' bin atomics are complete (they drained
        // before ticketing); atomics live at the device-coherent point,
        // read them with agent-scope atomic loads (bypass stale caches).
        float v = 0.f;
        for (int c = (int)threadIdx.x; c < CLS_NUM; c += 256) {
            unsigned cnt = __hip_atomic_load(&count[c], __ATOMIC_RELAXED,
                                             __HIP_MEMORY_SCOPE_AGENT);
            float ds = __hip_atomic_load(&distsum[c], __ATOMIC_RELAXED,
                                         __HIP_MEMORY_SCOPE_AGENT);
            if (cnt) v += ds / (float)cnt;
        }
        #pragma unroll
        for (int off = 32; off; off >>= 1)
            v += __shfl_xor(v, off, 64);
        __shared__ float wsum[4];
        if ((threadIdx.x & 63) == 0) wsum[threadIdx.x >> 6] = v;
        __syncthreads();
        if (threadIdx.x == 0)
            out[0] = wsum[0] + wsum[1] + wsum[2] + wsum[3];
    }
}

extern "C" void kernel_launch(void* const* d_in, const int* in_sizes, int n_in,
                              void* d_out, int out_size, void* d_ws, size_t ws_size,
                              hipStream_t stream)
{
    const float* xs     = (const float*)d_in[0];
    const void*  ys     = d_in[1];
    const float* center = (const float*)d_in[2];
    float* out = (float*)d_out;

    // ws layout: [0,4000) distsum ; [4096,8096) count ; [8192] arrival
    float* distsum        = (float*)d_ws;
    unsigned int* count   = (unsigned int*)((char*)d_ws + 4096);
    unsigned int* arrival = (unsigned int*)((char*)d_ws + 8192);

    const int n = in_sizes[1];  // number of samples (ys element count)

    hipMemsetAsync(d_ws, 0, 12288, stream);
    center_loss_fused<<<GRID, 256, 0, stream>>>(
        xs, ys, center, distsum, count, arrival, out, n);
}

// Round 12
// 57.122 us; speedup vs baseline: 1.8713x; 1.8713x over previous
//
#include <hip/hip_runtime.h>
#include <math.h>

#define CLS_NUM 1000
#define FEAT 512
#define GRID 2048

// R2-champion hot loop + last-block finalize with ZERO ordered operations.
// Lesson ledger:
//   R5:  per-thread __threadfence()          -> 372us (L2 wb/inv storm)
//   R11: per-block ACQ_REL agent fetch_add   -> 150us (same mechanism, fewer ops)
//   R2:  relaxed device atomics only         -> fast
// Ordering here relies on: (1) atomics complete AT the device-coherent point
// (never dirty in a non-coherent L2); (2) s_waitcnt vmcnt(0) retires a
// no-return atomic only when committed there; (3) relaxed agent-scope atomic
// loads read the coherent point directly (no buffer_inv emitted).
__global__ __launch_bounds__(256) void center_loss_fused(
    const float* __restrict__ xs,
    const void* __restrict__ ys_raw,
    const float* __restrict__ center,
    float* __restrict__ distsum,
    unsigned int* __restrict__ count,
    unsigned int* __restrict__ arrival,
    float* __restrict__ out,
    int n)
{
    // Detect int64 vs int32 labels (hi word zero across 16 slots ~ 1e-48 FP).
    const int* y32 = (const int*)ys_raw;
    bool is64 = true;
    #pragma unroll
    for (int k = 0; k < 16; ++k) {
        int lo = y32[2 * k], hi = y32[2 * k + 1];
        if (hi != 0 || (unsigned)lo >= (unsigned)CLS_NUM) is64 = false;
    }
    const long long* y64 = (const long long*)ys_raw;

    const int lane  = threadIdx.x & 63;
    const int wave  = (int)((blockIdx.x * blockDim.x + threadIdx.x) >> 6);
    const int nwave = (int)((gridDim.x * blockDim.x) >> 6);

    // ---- hot loop: byte-identical to the R2 champion ----
    for (int i = wave; i < n; i += nwave) {
        const int y = is64 ? (int)y64[i] : y32[i];
        const float4* xp = (const float4*)(xs + (size_t)i * FEAT);
        const float4* cp = (const float4*)(center + (size_t)y * FEAT);
        float4 x0 = xp[lane];
        float4 x1 = xp[lane + 64];
        float4 c0 = cp[lane];
        float4 c1 = cp[lane + 64];
        float d, s = 0.f;
        d = x0.x - c0.x; s += d * d;
        d = x0.y - c0.y; s += d * d;
        d = x0.z - c0.z; s += d * d;
        d = x0.w - c0.w; s += d * d;
        d = x1.x - c1.x; s += d * d;
        d = x1.y - c1.y; s += d * d;
        d = x1.z - c1.z; s += d * d;
        d = x1.w - c1.w; s += d * d;
        #pragma unroll
        for (int off = 32; off; off >>= 1)
            s += __shfl_xor(s, off, 64);
        if (lane == 0) {
            atomicAdd(&distsum[y], sqrtf(s));
            atomicAdd(&count[y], 1u);
        }
    }

    // ---- last-block finalize: relaxed-only ----
    asm volatile("s_waitcnt vmcnt(0)" ::: "memory");  // own atomics committed
    __syncthreads();

    __shared__ unsigned s_ticket;
    if (threadIdx.x == 0)
        s_ticket = atomicAdd(arrival, 1u);            // relaxed device-scope
    __syncthreads();

    if (s_ticket == (unsigned)(gridDim.x - 1)) {
        float v = 0.f;
        for (int c = (int)threadIdx.x; c < CLS_NUM; c += 256) {
            unsigned cnt = __hip_atomic_load(&count[c], __ATOMIC_RELAXED,
                                             __HIP_MEMORY_SCOPE_AGENT);
            float ds = __hip_atomic_load(&distsum[c], __ATOMIC_RELAXED,
                                         __HIP_MEMORY_SCOPE_AGENT);
            if (cnt) v += ds / (float)cnt;
        }
        #pragma unroll
        for (int off = 32; off; off >>= 1)
            v += __shfl_xor(v, off, 64);
        __shared__ float wsum[4];
        if ((threadIdx.x & 63) == 0) wsum[threadIdx.x >> 6] = v;
        __syncthreads();
        if (threadIdx.x == 0)
            out[0] = wsum[0] + wsum[1] + wsum[2] + wsum[3];
    }
}

extern "C" void kernel_launch(void* const* d_in, const int* in_sizes, int n_in,
                              void* d_out, int out_size, void* d_ws, size_t ws_size,
                              hipStream_t stream)
{
    const float* xs     = (const float*)d_in[0];
    const void*  ys     = d_in[1];
    const float* center = (const float*)d_in[2];
    float* out = (float*)d_out;

    // ws layout: [0,4000) distsum ; [4096,8096) count ; [8192] arrival
    float* distsum        = (float*)d_ws;
    unsigned int* count   = (unsigned int*)((char*)d_ws + 4096);
    unsigned int* arrival = (unsigned int*)((char*)d_ws + 8192);

    const int n = in_sizes[1];  // number of samples (ys element count)

    hipMemsetAsync(d_ws, 0, 12288, stream);
    center_loss_fused<<<GRID, 256, 0, stream>>>(
        xs, ys, center, distsum, count, arrival, out, n);
}

// Round 13
// 44.976 us; speedup vs baseline: 2.3767x; 1.2701x over previous
//
#include <hip/hip_runtime.h>
#include <math.h>

#define CLS_NUM 1000
#define FEAT 512

// R2-champion 3-node structure (memset -> dist -> final), with bins packed
// as interleaved {float distsum; uint count} 8-byte pairs:
//  - one contiguous 8000 B memset
//  - dist's two atomics land in the same 64 B line (1000 hot lines vs 2000)
//  - final reads one uint2 per class (1000 loads vs 2000, latency-bound node)
// Structural ledger (totals): R2 3-node 46.8 | count-first 57-60 | LDS-bins
// 60.8 | coop (container deaths) | fence finalize 372 | acq_rel 107 |
// relaxed finalize 57.1. All fusion attempts lose to the separate final node.

__global__ __launch_bounds__(256) void center_loss_dist(
    const float* __restrict__ xs,
    const void* __restrict__ ys_raw,
    const float* __restrict__ center,
    unsigned long long* __restrict__ bins,   // [CLS_NUM] {f32 ds, u32 cnt}
    int n)
{
    // Detect int64 vs int32 labels: for int64 (little-endian) the high
    // 32-bit word of each element is 0 and low word < 1000. For int32,
    // odd words are random labels; all-zero across 16 slots ~ 1e-48.
    const int* y32 = (const int*)ys_raw;
    bool is64 = true;
    #pragma unroll
    for (int k = 0; k < 16; ++k) {
        int lo = y32[2 * k], hi = y32[2 * k + 1];
        if (hi != 0 || (unsigned)lo >= (unsigned)CLS_NUM) is64 = false;
    }
    const long long* y64 = (const long long*)ys_raw;

    const int lane  = threadIdx.x & 63;
    const int wave  = (int)((blockIdx.x * blockDim.x + threadIdx.x) >> 6);
    const int nwave = (int)((gridDim.x * blockDim.x) >> 6);

    for (int i = wave; i < n; i += nwave) {
        const int y = is64 ? (int)y64[i] : y32[i];
        const float4* xp = (const float4*)(xs + (size_t)i * FEAT);
        const float4* cp = (const float4*)(center + (size_t)y * FEAT);
        // Fully coalesced: lane l reads float4 #l and #(l+64) of the row.
        float4 x0 = xp[lane];
        float4 x1 = xp[lane + 64];
        float4 c0 = cp[lane];
        float4 c1 = cp[lane + 64];
        float d, s = 0.f;
        d = x0.x - c0.x; s += d * d;
        d = x0.y - c0.y; s += d * d;
        d = x0.z - c0.z; s += d * d;
        d = x0.w - c0.w; s += d * d;
        d = x1.x - c1.x; s += d * d;
        d = x1.y - c1.y; s += d * d;
        d = x1.z - c1.z; s += d * d;
        d = x1.w - c1.w; s += d * d;
        #pragma unroll
        for (int off = 32; off; off >>= 1)
            s += __shfl_xor(s, off, 64);
        if (lane == 0) {
            float* dsp   = (float*)&bins[y];
            unsigned* cp2 = (unsigned*)&bins[y] + 1;
            atomicAdd(dsp, sqrtf(s));
            atomicAdd(cp2, 1u);
        }
    }
}

// out = sum_c ds_c / cnt_c  (cnt>0 guard; absent classes add 0)
__global__ __launch_bounds__(256) void center_loss_final(
    const unsigned long long* __restrict__ bins,
    float* __restrict__ out)
{
    float s = 0.f;
    for (int c = (int)threadIdx.x; c < CLS_NUM; c += 256) {
        unsigned long long p = bins[c];          // one 8 B load per class
        unsigned cnt = (unsigned)(p >> 32);
        float ds = __uint_as_float((unsigned)(p & 0xffffffffULL));
        if (cnt) s += ds / (float)cnt;
    }
    #pragma unroll
    for (int off = 32; off; off >>= 1)
        s += __shfl_xor(s, off, 64);
    __shared__ float wsum[4];
    if ((threadIdx.x & 63) == 0) wsum[threadIdx.x >> 6] = s;
    __syncthreads();
    if (threadIdx.x == 0)
        out[0] = wsum[0] + wsum[1] + wsum[2] + wsum[3];
}

extern "C" void kernel_launch(void* const* d_in, const int* in_sizes, int n_in,
                              void* d_out, int out_size, void* d_ws, size_t ws_size,
                              hipStream_t stream)
{
    const float* xs     = (const float*)d_in[0];
    const void*  ys     = d_in[1];
    const float* center = (const float*)d_in[2];
    float* out = (float*)d_out;

    // ws layout: bins[1000] = {f32 distsum, u32 count} pairs, 8000 bytes
    unsigned long long* bins = (unsigned long long*)d_ws;
    hipMemsetAsync(d_ws, 0, CLS_NUM * 8, stream);

    const int n = in_sizes[1];  // number of samples (ys element count)

    center_loss_dist<<<2048, 256, 0, stream>>>(xs, ys, center, bins, n);
    center_loss_final<<<1, 256, 0, stream>>>(bins, out);
}